// Round 13
// baseline (548.660 us; speedup 1.0000x reference)
//
#include <hip/hip_runtime.h>

#define M_DIM 8192
#define K_DIM 4096
#define N_DIM 11008
#define XSCALE 20.0f

typedef int i32x4  __attribute__((ext_vector_type(4)));
typedef unsigned char uchar;

// ---------- pre-pass 1: x fp32 -> i8 (round(x*20), clamp +-127) + exact int row sums ----------
__global__ __launch_bounds__(256) void k_quant_x(const float4* __restrict__ x,
                                                 int4* __restrict__ xq,
                                                 float* __restrict__ rs) {
    __shared__ int sred[4];
    const int row = blockIdx.x;
    const int t = threadIdx.x;
    const float4* src = x + (size_t)row * (K_DIM / 4) + t * 4;
    int o[4];
    int acc = 0;
#pragma unroll
    for (int c = 0; c < 4; ++c) {
        float4 v = src[c];
        int b0 = __float2int_rn(fmaxf(fminf(v.x * XSCALE, 127.f), -127.f));
        int b1 = __float2int_rn(fmaxf(fminf(v.y * XSCALE, 127.f), -127.f));
        int b2 = __float2int_rn(fmaxf(fminf(v.z * XSCALE, 127.f), -127.f));
        int b3 = __float2int_rn(fmaxf(fminf(v.w * XSCALE, 127.f), -127.f));
        acc += b0 + b1 + b2 + b3;
        o[c] = (b0 & 255) | ((b1 & 255) << 8) | ((b2 & 255) << 16) | ((b3 & 255) << 24);
    }
    xq[(size_t)row * 256 + t] = make_int4(o[0], o[1], o[2], o[3]);
#pragma unroll
    for (int off = 32; off >= 1; off >>= 1) acc += __shfl_down(acc, off);
    if ((t & 63) == 0) sred[t >> 6] = acc;
    __syncthreads();
    if (t == 0) rs[row] = (float)(sred[0] + sred[1] + sred[2] + sred[3]);
}

// ---------- pre-pass 2: qweight int32 (0..15) -> packed i8 ----------
__global__ __launch_bounds__(256) void k_pack_w(const int4* __restrict__ q, int4* __restrict__ wq) {
    size_t i = (size_t)blockIdx.x * 256 + threadIdx.x;   // 16 elems per thread
    int4 a = q[i * 4], b = q[i * 4 + 1], c = q[i * 4 + 2], d = q[i * 4 + 3];
    int4 o;
    o.x = a.x | (a.y << 8) | (a.z << 16) | (a.w << 24);
    o.y = b.x | (b.y << 8) | (b.z << 16) | (b.w << 24);
    o.z = c.x | (c.y << 8) | (c.z << 16) | (c.w << 24);
    o.w = d.x | (d.y << 8) | (d.z << 16) | (d.w << 24);
    wq[i] = o;
}

// ---------- 256x256 i8 GEMM, BK=64, 4-slot LDS ring, lead-1 register pipeline ----------
// S[m][n] = sum_k X[m][k]*Q[n][k] (exact);  y = (s/20)*S - (s*zp/20)*RS[m] + bias
// Window t (slot s=t&3, reg set p=t&1):
//   STAGE(t+2 -> slot (t+2)&3)          // 4 GLD16; target's readers drained 2 BARs ago
//   vmcnt(4)                            // drains tile t+1's stages (outstanding {t+1:4,t+2:4})
//   BAR                                 // publish t+1; all waves' reads of slot t&3 retired
//   LDA(t+1 -> set p^1)                 // 8 ds_reads, serviced UNDER this window's MFMAs
//   lgkmcnt(8)                          // drains A(t)+B(t) (12 oldest, FIFO); keeps A(t+1)
//   32x MFMA on set p (independent accs, setprio-bracketed)
//   LDB(t+1 -> bF)                      // 4 ds_reads after MFMA issue (bF reg WAR-safe)
// LDS slot: A 16KB + B 16KB; pair-interleave swizzle (R12 byte-exact, measured 0 conflicts).
using gcptr = const __attribute__((address_space(1))) void*;
using lptr  = __attribute__((address_space(3))) void*;
#define GLD16(gp, lp) __builtin_amdgcn_global_load_lds((gcptr)(gp), (lptr)(lp), 16, 0, 0)
#define BAR() asm volatile("s_barrier" ::: "memory")
#define LGKM8() do { asm volatile("s_waitcnt lgkmcnt(8)" ::: "memory"); \
                     __builtin_amdgcn_sched_barrier(0); } while (0)
#define LGKM0() do { asm volatile("s_waitcnt lgkmcnt(0)" ::: "memory"); \
                     __builtin_amdgcn_sched_barrier(0); } while (0)
#define VMW4() asm volatile("s_waitcnt vmcnt(4)" ::: "memory")
#define VMW0() asm volatile("s_waitcnt vmcnt(0)" ::: "memory")

__global__ __launch_bounds__(512, 2) void k_gemm(const uchar* __restrict__ A,
                                                 const uchar* __restrict__ B,
                                                 const float* __restrict__ rs,
                                                 const float* __restrict__ sc,
                                                 const float* __restrict__ zp,
                                                 const float* __restrict__ bias,
                                                 float* __restrict__ C) {
    constexpr int NT = K_DIM / 64;              // 64 K-tiles of BK=64 bytes
    constexpr int NBM = M_DIM / 256;            // 32
    constexpr int NWG = NBM * (N_DIM / 256);    // 1376, % 8 == 0

    __shared__ uchar lds[4][32768];             // slot: A @[0,16K), B @[16K,32K)

    // XCD-aware bijective swizzle
    int id = (blockIdx.x & 7) * (NWG / 8) + (blockIdx.x >> 3);
    const int bm = id & (NBM - 1);
    const int bn = id >> 5;

    const int tid = threadIdx.x;
    const int lane = tid & 63;
    const int w  = tid >> 6;     // wave 0..7
    const int wr = w >> 2;       // 0..1 (M): 128 rows
    const int wc = w & 3;        // 0..3 (N): 64 cols
    const int l15 = lane & 15;

    // ---- staging source (inverse pair-interleave swizzle; R12-proven) ----
    const int v    = (lane & 7) ^ ((lane >> 3) & 7);
    const int srow = w * 32 + 2 * (lane >> 3) + (v >> 2);   // 32 rows per wave
    const int scol = (v & 3) * 16;
    const uchar* aSrc = A + (size_t)(bm * 256 + srow) * K_DIM + scol;
    const uchar* bSrc = B + (size_t)(bn * 256 + srow) * K_DIM + scol;
    const int aDst = w * 2048;
    const int bDst = 16384 + w * 2048;

#define STAGE(t, s) do { \
        const size_t _ko = (size_t)(t) * 64; \
        GLD16(aSrc + _ko, &lds[s][aDst]); \
        GLD16(aSrc + (size_t)16 * K_DIM + _ko, &lds[s][aDst + 1024]); \
        GLD16(bSrc + _ko, &lds[s][bDst]); \
        GLD16(bSrc + (size_t)16 * K_DIM + _ko, &lds[s][bDst + 1024]); } while (0)

    // ---- frag-read addressing (R12-proven zero-conflict geometry) ----
    const int pc = ((lane >> 4) + 4 * (l15 & 1)) ^ ((l15 >> 1) & 7);
    const int fragOff = (l15 >> 1) * 128 + pc * 16;

    i32x4 aFA[8], aFB[8];      // ping-pong A sets (named: no runtime indexing)
    i32x4 bF[4];               // B frags (single set; WAR-safe reload after MFMA issue)
    i32x4 acc[8][4];           // 128 accumulators
#pragma unroll
    for (int j = 0; j < 8; ++j)
#pragma unroll
        for (int i = 0; i < 4; ++i) acc[j][i] = (i32x4){0, 0, 0, 0};

#define LDA_A(s) do { _Pragma("unroll") for (int mi = 0; mi < 8; ++mi) \
        aFA[mi] = *(const i32x4*)&lds[s][wr * 8192 + mi * 1024 + fragOff]; } while (0)
#define LDA_B(s) do { _Pragma("unroll") for (int mi = 0; mi < 8; ++mi) \
        aFB[mi] = *(const i32x4*)&lds[s][wr * 8192 + mi * 1024 + fragOff]; } while (0)
#define LDB4(s) do { _Pragma("unroll") for (int ni = 0; ni < 4; ++ni) \
        bF[ni] = *(const i32x4*)&lds[s][16384 + wc * 4096 + ni * 1024 + fragOff]; } while (0)

#define MFMA32(af) do { \
    __builtin_amdgcn_s_setprio(1); \
    _Pragma("unroll") for (int mi = 0; mi < 8; ++mi) \
    _Pragma("unroll") for (int ni = 0; ni < 4; ++ni) \
        acc[mi][ni] = __builtin_amdgcn_mfma_i32_16x16x64_i8(af[mi], bF[ni], acc[mi][ni], 0, 0, 0); \
    __builtin_amdgcn_s_setprio(0); \
    } while (0)

    // ---- prologue: stage tiles 0,1; publish 0; prime reads of tile 0 ----
    STAGE(0, 0);
    STAGE(1, 1);
    VMW4();                    // drains tile 0's 4; tile 1's 4 in flight
    BAR();
    LDA_A(0); LDB4(0);         // A(0) x8 then B(0) x4  (FIFO base for LGKM8)

    // ---- main loop: windows 0..59, guard-free; all slots/sets compile-time ----
    for (int t = 0; t < NT - 4; t += 4) {
        // window t   (set A, next->B, next slot 1)
        STAGE(t + 2, 2); VMW4(); BAR();
        LDA_B(1); LGKM8(); MFMA32(aFA); LDB4(1);
        // window t+1 (set B, next->A, next slot 2)
        STAGE(t + 3, 3); VMW4(); BAR();
        LDA_A(2); LGKM8(); MFMA32(aFB); LDB4(2);
        // window t+2 (set A, next->B, next slot 3)
        STAGE(t + 4, 0); VMW4(); BAR();
        LDA_B(3); LGKM8(); MFMA32(aFA); LDB4(3);
        // window t+3 (set B, next->A, next slot 0)
        STAGE(t + 5, 1); VMW4(); BAR();
        LDA_A(0); LGKM8(); MFMA32(aFB); LDB4(0);
    }
    // windows 60, 61 (still guard-free: stage 62, 63 valid)
    STAGE(62, 2); VMW4(); BAR();
    LDA_B(1); LGKM8(); MFMA32(aFA); LDB4(1);
    STAGE(63, 3); VMW4(); BAR();
    LDA_A(2); LGKM8(); MFMA32(aFB); LDB4(2);
    // window 62: no stage; publish tile 63 with full drain
    VMW0(); BAR();
    LDA_B(3); LGKM8(); MFMA32(aFA); LDB4(3);
    // window 63: final
    VMW0(); BAR();
    LGKM0(); MFMA32(aFB);

    // ---- epilogue: y = fs*S - fz*RS[row] + bias ----
    const float inv = 1.0f / XSCALE;
    float fsv[4], fzv[4], bvv[4];
    int colv[4];
#pragma unroll
    for (int i = 0; i < 4; ++i) {
        colv[i] = bn * 256 + wc * 64 + i * 16 + l15;
        fsv[i] = sc[colv[i]] * inv;
        fzv[i] = fsv[i] * zp[colv[i]];
        bvv[i] = bias[colv[i]];
    }
#pragma unroll
    for (int mi = 0; mi < 8; ++mi) {
        const int rowbase = bm * 256 + wr * 128 + mi * 16 + ((lane >> 4) << 2);
#pragma unroll
        for (int r = 0; r < 4; ++r) {
            const int row = rowbase + r;
            const float rsv = rs[row];
            float* cp = C + (size_t)row * N_DIM;
#pragma unroll
            for (int i = 0; i < 4; ++i)
                cp[colv[i]] = fsv[i] * (float)acc[mi][i][r] - fzv[i] * rsv + bvv[i];
        }
    }
#undef MFMA32
#undef LDA_A
#undef LDA_B
#undef LDB4
#undef STAGE
}

// ---------- fallback (ws too small): classic 16x16 fp32 tiled GEMM ----------
__global__ __launch_bounds__(256) void k_fb(const float* __restrict__ x, const int* __restrict__ q,
                                            const float* __restrict__ sc, const float* __restrict__ zp,
                                            const float* __restrict__ bias, float* __restrict__ C) {
    __shared__ float sX[16][17];
    __shared__ float sW[16][17];
    int tx = threadIdx.x & 15, ty = threadIdx.x >> 4;
    int m0 = blockIdx.y * 16, n0 = blockIdx.x * 16;
    int o = n0 + ty;
    float s = sc[o], z = zp[o];
    float acc = 0.f;
    for (int k0 = 0; k0 < K_DIM; k0 += 16) {
        sX[ty][tx] = x[(size_t)(m0 + ty) * K_DIM + k0 + tx];
        sW[ty][tx] = ((float)q[(size_t)o * K_DIM + k0 + tx] - z) * s;
        __syncthreads();
#pragma unroll
        for (int kk = 0; kk < 16; ++kk) acc += sX[ty][kk] * sW[tx][kk];
        __syncthreads();
    }
    C[(size_t)(m0 + ty) * N_DIM + n0 + tx] = acc + bias[n0 + tx];
}

extern "C" void kernel_launch(void* const* d_in, const int* in_sizes, int n_in,
                              void* d_out, int out_size, void* d_ws, size_t ws_size,
                              hipStream_t stream) {
    const float* x    = (const float*)d_in[0];
    const int*   qw   = (const int*)d_in[1];
    const float* sc   = (const float*)d_in[2];
    const float* zp   = (const float*)d_in[3];
    const float* bias = (const float*)d_in[4];
    float* out = (float*)d_out;

    const size_t xq_bytes = (size_t)M_DIM * K_DIM;        // 33,554,432
    const size_t wq_bytes = (size_t)N_DIM * K_DIM;        // 45,088,768
    const size_t rs_bytes = (size_t)M_DIM * 4;            // 32,768
    if (ws_size >= xq_bytes + wq_bytes + rs_bytes) {
        uchar* xq = (uchar*)d_ws;
        uchar* wq = xq + xq_bytes;
        float* rs = (float*)(wq + wq_bytes);
        k_quant_x<<<M_DIM, 256, 0, stream>>>((const float4*)x, (int4*)xq, rs);
        k_pack_w<<<N_DIM, 256, 0, stream>>>((const int4*)qw, (int4*)wq);
        k_gemm<<<(M_DIM / 256) * (N_DIM / 256), 512, 0, stream>>>(xq, wq, rs, sc, zp, bias, out);
    } else {
        dim3 g(N_DIM / 16, M_DIM / 16);
        k_fb<<<g, 256, 0, stream>>>(x, qw, sc, zp, bias, out);
    }
}

// Round 14
// 492.161 us; speedup vs baseline: 1.1148x; 1.1148x over previous
//
#include <hip/hip_runtime.h>

#define M_DIM 8192
#define K_DIM 4096
#define N_DIM 11008
#define XSCALE 20.0f

typedef int i32x4  __attribute__((ext_vector_type(4)));
typedef unsigned char uchar;

// ---------- pre-pass 1: x fp32 -> i8 (round(x*20), clamp +-127) + exact int row sums ----------
__global__ __launch_bounds__(256) void k_quant_x(const float4* __restrict__ x,
                                                 int4* __restrict__ xq,
                                                 float* __restrict__ rs) {
    __shared__ int sred[4];
    const int row = blockIdx.x;
    const int t = threadIdx.x;
    const float4* src = x + (size_t)row * (K_DIM / 4) + t * 4;
    int o[4];
    int acc = 0;
#pragma unroll
    for (int c = 0; c < 4; ++c) {
        float4 v = src[c];
        int b0 = __float2int_rn(fmaxf(fminf(v.x * XSCALE, 127.f), -127.f));
        int b1 = __float2int_rn(fmaxf(fminf(v.y * XSCALE, 127.f), -127.f));
        int b2 = __float2int_rn(fmaxf(fminf(v.z * XSCALE, 127.f), -127.f));
        int b3 = __float2int_rn(fmaxf(fminf(v.w * XSCALE, 127.f), -127.f));
        acc += b0 + b1 + b2 + b3;
        o[c] = (b0 & 255) | ((b1 & 255) << 8) | ((b2 & 255) << 16) | ((b3 & 255) << 24);
    }
    xq[(size_t)row * 256 + t] = make_int4(o[0], o[1], o[2], o[3]);
#pragma unroll
    for (int off = 32; off >= 1; off >>= 1) acc += __shfl_down(acc, off);
    if ((t & 63) == 0) sred[t >> 6] = acc;
    __syncthreads();
    if (t == 0) rs[row] = (float)(sred[0] + sred[1] + sred[2] + sred[3]);
}

// ---------- pre-pass 2: qweight int32 (0..15) -> packed i8 ----------
__global__ __launch_bounds__(256) void k_pack_w(const int4* __restrict__ q, int4* __restrict__ wq) {
    size_t i = (size_t)blockIdx.x * 256 + threadIdx.x;   // 16 elems per thread
    int4 a = q[i * 4], b = q[i * 4 + 1], c = q[i * 4 + 2], d = q[i * 4 + 3];
    int4 o;
    o.x = a.x | (a.y << 8) | (a.z << 16) | (a.w << 24);
    o.y = b.x | (b.y << 8) | (b.z << 16) | (b.w << 24);
    o.z = c.x | (c.y << 8) | (c.z << 16) | (c.w << 24);
    o.w = d.x | (d.y << 8) | (d.z << 16) | (d.w << 24);
    wq[i] = o;
}

// ---------- 256x256 i8 GEMM, BK=128, 16x16x64 -- R8 skeleton + cross-window read pipelining ----------
// S[m][n] = sum_k X[m][k]*Q[n][k] (exact);  y = (s/20)*S - (s*zp/20)*RS[m] + bias
// Read groups issue at the END of the window whose MFMA cluster last uses their target regs
// (operands latch at MFMA issue; sched_barrier(0) after each cluster pins program order):
//   P4(t): after Q(1,0) -> issue A0,B0,B1 of tile t+1 (16 ds_reads, buf^1)
//   P2(t): after Q(0,1) -> issue A1 of tile t       (8 ds_reads, buf)
// Counted drains: P1 lgkmcnt(4) [A0+B0 = oldest 12 of 16]; P2 lgkmcnt(0) [B1];
//                 P3 lgkmcnt(0) [A1].  4 barriers/tile (was 8).
// Stage schedule, vmcnt(8) ring, swizzle all unchanged from R8 (measured 0 conflicts).
using gcptr = const __attribute__((address_space(1))) void*;
using lptr  = __attribute__((address_space(3))) void*;
#define GLD16(gp, lp) __builtin_amdgcn_global_load_lds((gcptr)(gp), (lptr)(lp), 16, 0, 0)
#define BAR() asm volatile("s_barrier" ::: "memory")
#define SB0() __builtin_amdgcn_sched_barrier(0)
#define LGKM4() do { asm volatile("s_waitcnt lgkmcnt(4)" ::: "memory"); SB0(); } while (0)
#define LGKM0() do { asm volatile("s_waitcnt lgkmcnt(0)" ::: "memory"); SB0(); } while (0)
#define VMW8() asm volatile("s_waitcnt vmcnt(8)" ::: "memory")
#define VMW0() asm volatile("s_waitcnt vmcnt(0)" ::: "memory")

__global__ __launch_bounds__(512, 2) void k_gemm(const uchar* __restrict__ A,
                                                 const uchar* __restrict__ B,
                                                 const float* __restrict__ rs,
                                                 const float* __restrict__ sc,
                                                 const float* __restrict__ zp,
                                                 const float* __restrict__ bias,
                                                 float* __restrict__ C) {
    constexpr int NT = K_DIM / 128;             // 32 K-tiles of BK=128 bytes
    constexpr int NBM = M_DIM / 256;            // 32
    constexpr int NWG = NBM * (N_DIM / 256);    // 1376, % 8 == 0

    __shared__ uchar sA[2][256 * 128];          // 2 x 32 KB
    __shared__ uchar sB[2][256 * 128];          // 2 x 32 KB  (128 KB total)

    // XCD-aware bijective swizzle
    int id = (blockIdx.x & 7) * (NWG / 8) + (blockIdx.x >> 3);
    const int bm = id & (NBM - 1);
    const int bn = id >> 5;

    const int tid = threadIdx.x;
    const int lane = tid & 63;
    const int w  = tid >> 6;     // wave 0..7
    const int wr = w >> 2;       // 0..1 (M)
    const int wc = w & 3;        // 0..3 (N)

    // ---- staging source (pre-swizzled global chunk: c_src = c_lds ^ (row&7), 16B chunks) ----
    const int trow = tid >> 3;                                   // 0..63
    const int scol = ((tid & 7) ^ (trow & 7)) * 16;              // byte col
    const uchar* aBase = A + (size_t)(bm * 256 + trow) * K_DIM + scol;
    const uchar* bBase = B + (size_t)(bn * 256 + trow) * K_DIM + scol;
    const int ldsW = w * 1024;                                   // wave-uniform dest (bytes)

#define STAGE_A(kt, H, sbuf) do { if ((kt) < NT) { \
        const uchar* _s = aBase + (size_t)((H) * 128) * K_DIM + (kt) * 128; \
        uchar* _d = &sA[sbuf][(H) * 16384 + ldsW]; \
        GLD16(_s, _d); GLD16(_s + (size_t)64 * K_DIM, _d + 8192); } } while (0)
#define STAGE_B(kt, H, sbuf) do { if ((kt) < NT) { \
        const uchar* _s = bBase + (size_t)((H) * 128) * K_DIM + (kt) * 128; \
        uchar* _d = &sB[sbuf][(H) * 16384 + ldsW]; \
        GLD16(_s, _d); GLD16(_s + (size_t)64 * K_DIM, _d + 8192); } } while (0)

    // ---- ds_read lane addressing (swizzled, 16-row frags; R8 zero-conflict geometry) ----
    const int rowAb = (wr * 16 + (lane & 15)) * 128;   // byte offset of lane's row
    const int rowBb = (wc * 16 + (lane & 15)) * 128;
    const int cb  = lane >> 4;                         // chunk selector 0..3
    const int swz = lane & 7;                          // row&7 for this lane
#define CHUNK(ks) ((((ks) * 4 + cb) ^ swz) * 16)

    i32x4 aF[4][2];            // CURRENT A-half: 4 m-frags x 2 ks (reads issue after last consumer)
    i32x4 bF[2][2][2];         // BOTH B-halves: nh x 2 ii x 2 ks
    i32x4 acc[8][4];           // 8 m-frags x 4 n-frags (16x16 each)
#pragma unroll
    for (int j = 0; j < 8; ++j)
#pragma unroll
        for (int i = 0; i < 4; ++i) acc[j][i] = (i32x4){0, 0, 0, 0};

#define LDA(mh, buf) do { \
    _Pragma("unroll") for (int jj = 0; jj < 4; ++jj) \
    _Pragma("unroll") for (int ks = 0; ks < 2; ++ks) \
        aF[jj][ks] = *(const i32x4*)&sA[buf][(mh) * 16384 + jj * 4096 + rowAb + CHUNK(ks)]; \
    } while (0)
#define LDB(nh, buf) do { \
    _Pragma("unroll") for (int ii = 0; ii < 2; ++ii) \
    _Pragma("unroll") for (int ks = 0; ks < 2; ++ks) \
        bF[nh][ii][ks] = *(const i32x4*)&sB[buf][(nh) * 16384 + ii * 8192 + rowBb + CHUNK(ks)]; \
    } while (0)
    // ks outer: 8 independent MFMAs then their ks=1 partners (dep distance 8)
#define MFMA_Q(mh, nh) do { \
    __builtin_amdgcn_s_setprio(1); \
    _Pragma("unroll") for (int ks = 0; ks < 2; ++ks) \
    _Pragma("unroll") for (int jj = 0; jj < 4; ++jj) \
    _Pragma("unroll") for (int ii = 0; ii < 2; ++ii) \
        acc[(mh) * 4 + jj][(nh) * 2 + ii] = __builtin_amdgcn_mfma_i32_16x16x64_i8( \
            aF[jj][ks], bF[nh][ii][ks], acc[(mh) * 4 + jj][(nh) * 2 + ii], 0, 0, 0); \
    __builtin_amdgcn_s_setprio(0); \
    SB0(); \
    } while (0)

    // ---- prologue: stage tiles 0,1 fully; publish t0; prime A0,B0,B1 of t0 ----
    STAGE_A(0, 0, 0); STAGE_B(0, 0, 0); STAGE_B(0, 1, 0); STAGE_A(0, 1, 0);
    STAGE_A(1, 0, 1); STAGE_B(1, 0, 1); STAGE_B(1, 1, 1); STAGE_A(1, 1, 1);
    VMW8();          // t0's 8 retired; t1's 8 in flight
    BAR();
    LDA(0, 0); LDB(0, 0);      // group 1: A0+B0 (12 reads)
    SB0();
    LDB(1, 0);                 // group 2: B1 (4 reads)  -- fenced: FIFO order matters

    // ---- main loop: 4 windows/tile, 4 barriers/tile, counted lgkm drains ----
#define GROUP(g, buf) do { \
    /* P1: Q(0,0). A0,B0 issued at P4(t-1) -- drain oldest 12, keep B1 in flight */ \
    LGKM4(); \
    MFMA_Q(0, 0); \
    BAR(); \
    /* P2: Q(0,1). B1 issued a full tile ago -- free drain. Then issue A1(t). */ \
    STAGE_A((g) + 2, 0, buf); STAGE_B((g) + 2, 0, buf); \
    LGKM0(); \
    MFMA_Q(0, 1); \
    LDA(1, buf);                       /* A1(t): aF regs free after Q(0,1) issue */ \
    BAR(); \
    /* P3: Q(1,1). A1 had P2-tail + stage to complete. */ \
    STAGE_B((g) + 2, 1, buf); \
    LGKM0(); \
    MFMA_Q(1, 1); \
    BAR(); \
    /* P4: publish t+1; Q(1,0); issue A0,B0,B1 of t+1 from buf^1 */ \
    STAGE_A((g) + 2, 1, buf); \
    if ((g) >= NT - 3) { VMW0(); } else { VMW8(); } \
    BAR(); \
    MFMA_Q(1, 0); \
    if ((g) + 1 < NT) { \
        LDA(0, (buf) ^ 1); LDB(0, (buf) ^ 1); \
        SB0(); \
        LDB(1, (buf) ^ 1); \
    } \
    } while (0)

    for (int g = 0; g < NT; g += 2) {
        GROUP(g, 0);
        GROUP(g + 1, 1);
    }

    // ---- epilogue: y = fs*S - fz*RS[row] + bias ----
    const float inv = 1.0f / XSCALE;
    float fsv[4], fzv[4], bvv[4];
    int colv[4];
#pragma unroll
    for (int i = 0; i < 4; ++i) {
        colv[i] = bn * 256 + 16 * wc + 64 * i + (lane & 15);
        fsv[i] = sc[colv[i]] * inv;
        fzv[i] = fsv[i] * zp[colv[i]];
        bvv[i] = bias[colv[i]];
    }
#pragma unroll
    for (int j = 0; j < 8; ++j) {
        const int rowbase = bm * 256 + 16 * wr + 32 * j + ((lane >> 4) << 2);
#pragma unroll
        for (int r = 0; r < 4; ++r) {
            const int row = rowbase + r;
            const float rsv = rs[row];
            float* cp = C + (size_t)row * N_DIM;
#pragma unroll
            for (int i = 0; i < 4; ++i)
                cp[colv[i]] = fsv[i] * (float)acc[j][i][r] - fzv[i] * rsv + bvv[i];
        }
    }
#undef GROUP
#undef MFMA_Q
#undef LDA
#undef LDB
#undef CHUNK
#undef STAGE_A
#undef STAGE_B
}

// ---------- fallback (ws too small): classic 16x16 fp32 tiled GEMM ----------
__global__ __launch_bounds__(256) void k_fb(const float* __restrict__ x, const int* __restrict__ q,
                                            const float* __restrict__ sc, const float* __restrict__ zp,
                                            const float* __restrict__ bias, float* __restrict__ C) {
    __shared__ float sX[16][17];
    __shared__ float sW[16][17];
    int tx = threadIdx.x & 15, ty = threadIdx.x >> 4;
    int m0 = blockIdx.y * 16, n0 = blockIdx.x * 16;
    int o = n0 + ty;
    float s = sc[o], z = zp[o];
    float acc = 0.f;
    for (int k0 = 0; k0 < K_DIM; k0 += 16) {
        sX[ty][tx] = x[(size_t)(m0 + ty) * K_DIM + k0 + tx];
        sW[ty][tx] = ((float)q[(size_t)o * K_DIM + k0 + tx] - z) * s;
        __syncthreads();
#pragma unroll
        for (int kk = 0; kk < 16; ++kk) acc += sX[ty][kk] * sW[tx][kk];
        __syncthreads();
    }
    C[(size_t)(m0 + ty) * N_DIM + n0 + tx] = acc + bias[n0 + tx];
}

extern "C" void kernel_launch(void* const* d_in, const int* in_sizes, int n_in,
                              void* d_out, int out_size, void* d_ws, size_t ws_size,
                              hipStream_t stream) {
    const float* x    = (const float*)d_in[0];
    const int*   qw   = (const int*)d_in[1];
    const float* sc   = (const float*)d_in[2];
    const float* zp   = (const float*)d_in[3];
    const float* bias = (const float*)d_in[4];
    float* out = (float*)d_out;

    const size_t xq_bytes = (size_t)M_DIM * K_DIM;        // 33,554,432
    const size_t wq_bytes = (size_t)N_DIM * K_DIM;        // 45,088,768
    const size_t rs_bytes = (size_t)M_DIM * 4;            // 32,768
    if (ws_size >= xq_bytes + wq_bytes + rs_bytes) {
        uchar* xq = (uchar*)d_ws;
        uchar* wq = xq + xq_bytes;
        float* rs = (float*)(wq + wq_bytes);
        k_quant_x<<<M_DIM, 256, 0, stream>>>((const float4*)x, (int4*)xq, rs);
        k_pack_w<<<N_DIM, 256, 0, stream>>>((const int4*)qw, (int4*)wq);
        k_gemm<<<(M_DIM / 256) * (N_DIM / 256), 512, 0, stream>>>(xq, wq, rs, sc, zp, bias, out);
    } else {
        dim3 g(N_DIM / 16, M_DIM / 16);
        k_fb<<<g, 256, 0, stream>>>(x, qw, sc, zp, bias, out);
    }
}